// Round 1
// baseline (404.578 us; speedup 1.0000x reference)
//
#include <hip/hip_runtime.h>
#include <hip/hip_bf16.h>

// NoisyActLin: y = fakequant(x) @ fakequant(W).T + bias
// x: [4,2048,2048] f32 -> M=8192, K=2048 ; W: [8192,2048] f32 -> N=8192
// out: [8192, 8192] f32

using f16x8 = __attribute__((ext_vector_type(8))) _Float16;
using f32x4 = __attribute__((ext_vector_type(4))) float;

#define AS1 __attribute__((address_space(1)))
#define AS3 __attribute__((address_space(3)))

static __device__ __forceinline__ void gload_lds16(const void* g, void* l) {
    __builtin_amdgcn_global_load_lds((const AS1 void*)g, (AS3 void*)l, 16, 0, 0);
}

// ---------------- weight fake-quant: one block per row ----------------
__global__ __launch_bounds__(256) void wquant_kernel(
    const float* __restrict__ W, const float* __restrict__ lws,
    _Float16* __restrict__ Wq) {
    constexpr int K = 2048;
    const int row = blockIdx.x;
    const int t = threadIdx.x;
    const float* w = W + (size_t)row * K;

    float4 v0 = ((const float4*)w)[t * 2];
    float4 v1 = ((const float4*)w)[t * 2 + 1];
    float vals[8] = {v0.x, v0.y, v0.z, v0.w, v1.x, v1.y, v1.z, v1.w};

    float mn = vals[0], mx = vals[0];
#pragma unroll
    for (int i = 1; i < 8; ++i) {
        mn = fminf(mn, vals[i]);
        mx = fmaxf(mx, vals[i]);
    }
#pragma unroll
    for (int off = 32; off >= 1; off >>= 1) {
        mn = fminf(mn, __shfl_xor(mn, off));
        mx = fmaxf(mx, __shfl_xor(mx, off));
    }
    __shared__ float smn[4], smx[4];
    if ((t & 63) == 0) { smn[t >> 6] = mn; smx[t >> 6] = mx; }
    __syncthreads();
    mn = fminf(fminf(smn[0], smn[1]), fminf(smn[2], smn[3]));
    mx = fmaxf(fmaxf(smx[0], smx[1]), fmaxf(smx[2], smx[3]));

    const float l = lws[row];
    const float ws = exp2f(l);     // power of two -> exact
    const float rs = exp2f(-l);    // exact reciprocal
    // qwmin/qwmax: round(min / s * 2) / 2 * s   (WGT_GUARD = 2)
    const float qwmin = rintf(mn * rs * 2.0f) * 0.5f * ws;
    const float qwmax = rintf(mx * rs * 2.0f) * 0.5f * ws;

    f16x8 out;
#pragma unroll
    for (int i = 0; i < 8; ++i) {
        float c = fminf(fmaxf(vals[i], qwmin), qwmax);
        float qw = rintf((c - qwmin) * rs);   // == (c - qwmin)/ws exactly
        out[i] = (_Float16)(qw * ws + qwmin);
    }
    *(f16x8*)&Wq[(size_t)row * K + (size_t)t * 8] = out;
}

// ---------------- activation fake-quant: elementwise ----------------
__global__ __launch_bounds__(256) void xquant_kernel(
    const float* __restrict__ X,
    const float* __restrict__ las, const float* __restrict__ laq,
    const float* __restrict__ ab, _Float16* __restrict__ Xq) {
    const float ls = las[0], lq = laq[0];
    const float s = exp2f(ls);
    const float rs = exp2f(-ls);
    const float q = exp2f(lq);
    const float zp = rintf(ab[0] * rs * 2.0f) * 0.5f * s;  // ACT_GUARD = 2
    const float lo = zp;
    const float hi = (zp + q) - s;

    const size_t base = ((size_t)blockIdx.x * 256 + threadIdx.x) * 8;
    float4 v0 = *(const float4*)&X[base];
    float4 v1 = *(const float4*)&X[base + 4];
    float vals[8] = {v0.x, v0.y, v0.z, v0.w, v1.x, v1.y, v1.z, v1.w};

    f16x8 out;
#pragma unroll
    for (int i = 0; i < 8; ++i) {
        float c = fminf(fmaxf(vals[i], lo), hi);
        float qx = rintf((c - zp) * rs);      // == (c - zp)/s exactly
        out[i] = (_Float16)(qx * s + zp);
    }
    *(f16x8*)&Xq[base] = out;
}

// ---------------- GEMM: C[M][N] = A[M][K] * B[N][K]^T + bias ----------------
// m97 structure: 128x128 tile, BK=32, 4 waves (2x2), each wave 64x64 (4x4 frags),
// global_load_lds width-16 staging, 2 barriers per K-step, XCD swizzle.
__global__ __launch_bounds__(256, 2) void gemm_kernel(
    const _Float16* __restrict__ A, const _Float16* __restrict__ B,
    const float* __restrict__ bias, float* __restrict__ C) {
    constexpr int M = 8192, N = 8192, K = 2048;
    constexpr int BM = 128, BN = 128, BK = 32;
    constexpr int NBN = N / BN;          // 64
    constexpr int KT = K / BK;           // 64

    __shared__ _Float16 As[BM * BK];     // 8 KB
    __shared__ _Float16 Bs[BN * BK];     // 8 KB

    // XCD-aware swizzle (nwg = 4096, divisible by 8 -> bijective)
    const int nwg = gridDim.x;
    const int cpx = nwg >> 3;
    const int bid = blockIdx.x;
    const int swz = (bid & 7) * cpx + (bid >> 3);
    const int bm = swz / NBN;
    const int bn = swz % NBN;

    const int t = threadIdx.x;
    const int lane = t & 63;
    const int wave = t >> 6;
    const int wr = wave >> 1;            // 0..1
    const int wc = wave & 1;             // 0..1
    const int l15 = lane & 15;
    const int lq = lane >> 4;

    const _Float16* Abase = A + (size_t)bm * BM * K;
    const _Float16* Bbase = B + (size_t)bn * BN * K;

    f32x4 acc[4][4] = {};

    for (int kt = 0; kt < KT; ++kt) {
        const int k0 = kt * BK;
        __syncthreads();   // previous compute done before LDS overwrite
#pragma unroll
        for (int is = 0; is < 2; ++is) {
            const int c = is * 256 + t;            // chunk id, 0..511
            const int r = c >> 2;                  // row 0..127
            const int kk = (c & 3) * 8;            // k element offset in tile
            gload_lds16(Abase + (size_t)r * K + k0 + kk, &As[c * 8]);
            gload_lds16(Bbase + (size_t)r * K + k0 + kk, &Bs[c * 8]);
        }
        __syncthreads();   // drains vmcnt(0), data visible

        f16x8 af[4], bf[4];
#pragma unroll
        for (int i = 0; i < 4; ++i) {
            af[i] = *(const f16x8*)&As[(wr * 64 + i * 16 + l15) * BK + lq * 8];
            bf[i] = *(const f16x8*)&Bs[(wc * 64 + i * 16 + l15) * BK + lq * 8];
        }
#pragma unroll
        for (int i = 0; i < 4; ++i)
#pragma unroll
            for (int j = 0; j < 4; ++j)
                acc[i][j] = __builtin_amdgcn_mfma_f32_16x16x32_f16(
                    af[i], bf[j], acc[i][j], 0, 0, 0);
    }

    // epilogue: D lane mapping col=lane&15, row=(lane>>4)*4+reg  [m89-verified]
#pragma unroll
    for (int i = 0; i < 4; ++i) {
        const int row = bm * BM + wr * 64 + i * 16 + lq * 4;
#pragma unroll
        for (int j = 0; j < 4; ++j) {
            const int col = bn * BN + wc * 64 + j * 16 + l15;
            const float bv = bias[col];
#pragma unroll
            for (int r = 0; r < 4; ++r) {
                C[(size_t)(row + r) * N + col] = acc[i][j][r] + bv;
            }
        }
    }
}

extern "C" void kernel_launch(void* const* d_in, const int* in_sizes, int n_in,
                              void* d_out, int out_size, void* d_ws, size_t ws_size,
                              hipStream_t stream) {
    const float* x    = (const float*)d_in[0];   // [4,2048,2048]
    const float* w    = (const float*)d_in[1];   // [8192,2048]
    const float* bias = (const float*)d_in[2];   // [8192]
    const float* las  = (const float*)d_in[3];   // log_act_s [1]
    const float* laq  = (const float*)d_in[4];   // log_act_q [1]
    const float* ab   = (const float*)d_in[5];   // act_b [1]
    const float* lws  = (const float*)d_in[6];   // log_wght_s [8192]
    float* out = (float*)d_out;

    constexpr size_t MK = (size_t)8192 * 2048;   // x elems
    constexpr size_t NK = (size_t)8192 * 2048;   // w elems
    _Float16* xq = (_Float16*)d_ws;
    _Float16* wq = (_Float16*)((char*)d_ws + MK * sizeof(_Float16));

    xquant_kernel<<<8192, 256, 0, stream>>>(x, las, laq, ab, xq);
    wquant_kernel<<<8192, 256, 0, stream>>>(w, lws, wq);
    gemm_kernel<<<4096, 256, 0, stream>>>(xq, wq, bias, out);
}

// Round 2
// 334.573 us; speedup vs baseline: 1.2092x; 1.2092x over previous
//
#include <hip/hip_runtime.h>
#include <hip/hip_bf16.h>

// NoisyActLin: y = fakequant(x) @ fakequant(W).T + bias
// x: [4,2048,2048] f32 -> M=8192, K=2048 ; W: [8192,2048] f32 -> N=8192
// out: [8192, 8192] f32
//
// GEMM: 256x256 tile, BK=64, 8 waves, 8-phase schedule (T2 st_16x32 swizzle +
// T3/T4 counted vmcnt(6) + T5 setprio), f16 inputs, fp32 accum.

using f16x8 = __attribute__((ext_vector_type(8))) _Float16;
using f32x4 = __attribute__((ext_vector_type(4))) float;

#define AS1 __attribute__((address_space(1)))
#define AS3 __attribute__((address_space(3)))

static __device__ __forceinline__ void gload_lds16(const void* g, void* l) {
    __builtin_amdgcn_global_load_lds((const AS1 void*)g, (AS3 void*)l, 16, 0, 0);
}

// ---------------- weight fake-quant: one block per row ----------------
__global__ __launch_bounds__(256) void wquant_kernel(
    const float* __restrict__ W, const float* __restrict__ lws,
    _Float16* __restrict__ Wq) {
    constexpr int K = 2048;
    const int row = blockIdx.x;
    const int t = threadIdx.x;
    const float* w = W + (size_t)row * K;

    float4 v0 = ((const float4*)w)[t * 2];
    float4 v1 = ((const float4*)w)[t * 2 + 1];
    float vals[8] = {v0.x, v0.y, v0.z, v0.w, v1.x, v1.y, v1.z, v1.w};

    float mn = vals[0], mx = vals[0];
#pragma unroll
    for (int i = 1; i < 8; ++i) {
        mn = fminf(mn, vals[i]);
        mx = fmaxf(mx, vals[i]);
    }
#pragma unroll
    for (int off = 32; off >= 1; off >>= 1) {
        mn = fminf(mn, __shfl_xor(mn, off));
        mx = fmaxf(mx, __shfl_xor(mx, off));
    }
    __shared__ float smn[4], smx[4];
    if ((t & 63) == 0) { smn[t >> 6] = mn; smx[t >> 6] = mx; }
    __syncthreads();
    mn = fminf(fminf(smn[0], smn[1]), fminf(smn[2], smn[3]));
    mx = fmaxf(fmaxf(smx[0], smx[1]), fmaxf(smx[2], smx[3]));

    const float l = lws[row];
    const float ws = exp2f(l);     // power of two -> exact
    const float rs = exp2f(-l);    // exact reciprocal
    const float qwmin = rintf(mn * rs * 2.0f) * 0.5f * ws;
    const float qwmax = rintf(mx * rs * 2.0f) * 0.5f * ws;

    f16x8 out;
#pragma unroll
    for (int i = 0; i < 8; ++i) {
        float c = fminf(fmaxf(vals[i], qwmin), qwmax);
        float qw = rintf((c - qwmin) * rs);
        out[i] = (_Float16)(qw * ws + qwmin);
    }
    *(f16x8*)&Wq[(size_t)row * K + (size_t)t * 8] = out;
}

// ---------------- activation fake-quant: elementwise ----------------
__global__ __launch_bounds__(256) void xquant_kernel(
    const float* __restrict__ X,
    const float* __restrict__ las, const float* __restrict__ laq,
    const float* __restrict__ ab, _Float16* __restrict__ Xq) {
    const float ls = las[0], lq = laq[0];
    const float s = exp2f(ls);
    const float rs = exp2f(-ls);
    const float q = exp2f(lq);
    const float zp = rintf(ab[0] * rs * 2.0f) * 0.5f * s;
    const float lo = zp;
    const float hi = (zp + q) - s;

    const size_t base = ((size_t)blockIdx.x * 256 + threadIdx.x) * 8;
    float4 v0 = *(const float4*)&X[base];
    float4 v1 = *(const float4*)&X[base + 4];
    float vals[8] = {v0.x, v0.y, v0.z, v0.w, v1.x, v1.y, v1.z, v1.w};

    f16x8 out;
#pragma unroll
    for (int i = 0; i < 8; ++i) {
        float c = fminf(fmaxf(vals[i], lo), hi);
        float qx = rintf((c - zp) * rs);
        out[i] = (_Float16)(qx * s + zp);
    }
    *(f16x8*)&Xq[base] = out;
}

// ---------------- GEMM: C[M][N] = A[M][K] * B[N][K]^T + bias ----------------
// 256x256 tile, BK=64 split into two K-halves (ks) of 32.
// LDS per matrix: 4 ring slots [dbuf(kt&1)][ks] of 256x32 f16 = 16 KB each.
// st_16x32 swizzle: byte ^= ((byte>>9)&1)<<5 within each slot, applied via
// pre-swizzled global source (linear global_load_lds dest) + swizzled ds_read.
// Per K-tile: 4 phases (ks,mh); stage order kt+1.A1 / kt+2.B0 / kt+2.A0 /
// kt+2.B1 (each slot's last reader finished one phase earlier, behind a
// barrier). One vmcnt(6) per K-tile (3 half-tiles in flight).
__global__ __launch_bounds__(512, 2) void gemm_kernel(
    const _Float16* __restrict__ A, const _Float16* __restrict__ B,
    const float* __restrict__ bias, float* __restrict__ C) {
    constexpr int N = 8192, K = 2048;
    constexpr int KT = K / 64;          // 32 K-tiles
    constexpr int NBN = N / 256;        // 32

    __shared__ char smem[131072];       // 128 KiB
    char* As = smem;                    // 4 x 16384
    char* Bs = smem + 65536;            // 4 x 16384

    // XCD-aware swizzle (nwg = 1024, %8 == 0 -> bijective)
    const int bid = blockIdx.x;
    const int cpx = gridDim.x >> 3;
    const int swzb = (bid & 7) * cpx + (bid >> 3);
    const int bm = swzb / NBN;
    const int bn = swzb % NBN;

    const int t = threadIdx.x;
    const int lane = t & 63;
    const int wid = t >> 6;
    const int wr = wid >> 2;            // 0..1 (M)
    const int wc = wid & 3;             // 0..3 (N)
    const int l15 = lane & 15;
    const int lq = lane >> 4;

    // ---- staging constants: chunk c covers LDS bytes c*16..+15 (linear dest).
    // element there = linear pos (c*16) ^ swizzle -> global (row, col).
    const int c0 = t, c1 = t + 512;
    const int d0 = c0 * 16, d1 = c1 * 16;
    const int eoff0 = (d0 >> 6) * K + (((d0 & 63) ^ (((d0 >> 9) & 1) << 5)) >> 1);
    const int eoff1 = (d1 >> 6) * K + (((d1 & 63) ^ (((d1 >> 9) & 1) << 5)) >> 1);
    const _Float16* Agb = A + (size_t)bm * 256 * K;
    const _Float16* Bgb = B + (size_t)bn * 256 * K;

    // ---- read-side swizzled column offset (row bit3 == l15 bit3)
    const int colpart = (lq * 16) ^ ((l15 & 8) << 2);

    f32x4 acc[8][4] = {};

#define STAGE(gb, lm, ktSlot, ktSrc, ks) do {                                  \
        const _Float16* _g = (gb) + ((size_t)(ktSrc) * 64 + (ks) * 32);        \
        char* _l = (lm) + ((((ktSlot) & 1) * 2 + (ks)) * 16384);               \
        gload_lds16(_g + eoff0, _l + d0);                                      \
        gload_lds16(_g + eoff1, _l + d1);                                      \
    } while (0)

    // ---- prologue: issue kt0 all + kt1.{B0,A0,B1}; wait kt0 landed ----
    STAGE(Bgb, Bs, 0, 0, 0);
    STAGE(Agb, As, 0, 0, 0);
    STAGE(Bgb, Bs, 0, 0, 1);
    STAGE(Agb, As, 0, 0, 1);
    STAGE(Bgb, Bs, 1, 1, 0);
    STAGE(Agb, As, 1, 1, 0);
    STAGE(Bgb, Bs, 1, 1, 1);
    asm volatile("s_waitcnt vmcnt(6)" ::: "memory");
    __builtin_amdgcn_s_barrier();

    for (int kt = 0; kt < KT; ++kt) {
        const int db = (kt & 1) * 2;
        const int s1 = kt + 1, s2 = kt + 2;
        const int s1c = (s1 < KT) ? s1 : (KT - 1);
        const int s2c = (s2 < KT) ? s2 : (KT - 1);

        f16x8 bf[4], af[4];

        // ===== phase 1: ks=0, mh=0 ; stage kt+1.A1 =====
        {
            const char* Bsl = Bs + (db + 0) * 16384;
            const char* Asl = As + (db + 0) * 16384;
#pragma unroll
            for (int n = 0; n < 4; ++n)
                bf[n] = *(const f16x8*)(Bsl + (wc * 64 + n * 16 + l15) * 64 + colpart);
#pragma unroll
            for (int m = 0; m < 4; ++m)
                af[m] = *(const f16x8*)(Asl + (wr * 128 + m * 16 + l15) * 64 + colpart);
            STAGE(Agb, As, s1, s1c, 1);
            __builtin_amdgcn_s_barrier();
            asm volatile("s_waitcnt lgkmcnt(0)" ::: "memory");
            __builtin_amdgcn_sched_barrier(0);
            __builtin_amdgcn_s_setprio(1);
#pragma unroll
            for (int m = 0; m < 4; ++m)
#pragma unroll
                for (int n = 0; n < 4; ++n)
                    acc[m][n] = __builtin_amdgcn_mfma_f32_16x16x32_f16(
                        af[m], bf[n], acc[m][n], 0, 0, 0);
            __builtin_amdgcn_s_setprio(0);
            __builtin_amdgcn_s_barrier();
        }
        // ===== phase 2: ks=0, mh=1 ; stage kt+2.B0 =====
        {
            const char* Asl = As + (db + 0) * 16384;
#pragma unroll
            for (int m = 0; m < 4; ++m)
                af[m] = *(const f16x8*)(Asl + (wr * 128 + 64 + m * 16 + l15) * 64 + colpart);
            STAGE(Bgb, Bs, s2, s2c, 0);
            __builtin_amdgcn_s_barrier();
            asm volatile("s_waitcnt lgkmcnt(0)" ::: "memory");
            __builtin_amdgcn_sched_barrier(0);
            __builtin_amdgcn_s_setprio(1);
#pragma unroll
            for (int m = 0; m < 4; ++m)
#pragma unroll
                for (int n = 0; n < 4; ++n)
                    acc[4 + m][n] = __builtin_amdgcn_mfma_f32_16x16x32_f16(
                        af[m], bf[n], acc[4 + m][n], 0, 0, 0);
            __builtin_amdgcn_s_setprio(0);
            __builtin_amdgcn_s_barrier();
        }
        // ===== phase 3: ks=1, mh=0 ; stage kt+2.A0 =====
        {
            const char* Bsl = Bs + (db + 1) * 16384;
            const char* Asl = As + (db + 1) * 16384;
#pragma unroll
            for (int n = 0; n < 4; ++n)
                bf[n] = *(const f16x8*)(Bsl + (wc * 64 + n * 16 + l15) * 64 + colpart);
#pragma unroll
            for (int m = 0; m < 4; ++m)
                af[m] = *(const f16x8*)(Asl + (wr * 128 + m * 16 + l15) * 64 + colpart);
            STAGE(Agb, As, s2, s2c, 0);
            __builtin_amdgcn_s_barrier();
            asm volatile("s_waitcnt lgkmcnt(0)" ::: "memory");
            __builtin_amdgcn_sched_barrier(0);
            __builtin_amdgcn_s_setprio(1);
#pragma unroll
            for (int m = 0; m < 4; ++m)
#pragma unroll
                for (int n = 0; n < 4; ++n)
                    acc[m][n] = __builtin_amdgcn_mfma_f32_16x16x32_f16(
                        af[m], bf[n], acc[m][n], 0, 0, 0);
            __builtin_amdgcn_s_setprio(0);
            __builtin_amdgcn_s_barrier();
        }
        // ===== phase 4: ks=1, mh=1 ; stage kt+2.B1 ; vmcnt(6) =====
        {
            const char* Asl = As + (db + 1) * 16384;
#pragma unroll
            for (int m = 0; m < 4; ++m)
                af[m] = *(const f16x8*)(Asl + (wr * 128 + 64 + m * 16 + l15) * 64 + colpart);
            STAGE(Bgb, Bs, s2, s2c, 1);
            __builtin_amdgcn_s_barrier();
            asm volatile("s_waitcnt lgkmcnt(0)" ::: "memory");
            __builtin_amdgcn_sched_barrier(0);
            __builtin_amdgcn_s_setprio(1);
#pragma unroll
            for (int m = 0; m < 4; ++m)
#pragma unroll
                for (int n = 0; n < 4; ++n)
                    acc[4 + m][n] = __builtin_amdgcn_mfma_f32_16x16x32_f16(
                        af[m], bf[n], acc[4 + m][n], 0, 0, 0);
            __builtin_amdgcn_s_setprio(0);
            asm volatile("s_waitcnt vmcnt(6)" ::: "memory");
            __builtin_amdgcn_s_barrier();
        }
    }
#undef STAGE

    // ---- epilogue: C/D mapping col=lane&15, row=(lane>>4)*4+reg ----
#pragma unroll
    for (int m = 0; m < 8; ++m) {
        const int row = bm * 256 + wr * 128 + m * 16 + lq * 4;
#pragma unroll
        for (int n = 0; n < 4; ++n) {
            const int col = bn * 256 + wc * 64 + n * 16 + l15;
            const float bv = bias[col];
#pragma unroll
            for (int r = 0; r < 4; ++r) {
                C[(size_t)(row + r) * N + col] = acc[m][n][r] + bv;
            }
        }
    }
}

extern "C" void kernel_launch(void* const* d_in, const int* in_sizes, int n_in,
                              void* d_out, int out_size, void* d_ws, size_t ws_size,
                              hipStream_t stream) {
    const float* x    = (const float*)d_in[0];   // [4,2048,2048]
    const float* w    = (const float*)d_in[1];   // [8192,2048]
    const float* bias = (const float*)d_in[2];   // [8192]
    const float* las  = (const float*)d_in[3];   // log_act_s [1]
    const float* laq  = (const float*)d_in[4];   // log_act_q [1]
    const float* ab   = (const float*)d_in[5];   // act_b [1]
    const float* lws  = (const float*)d_in[6];   // log_wght_s [8192]
    float* out = (float*)d_out;

    constexpr size_t MK = (size_t)8192 * 2048;
    _Float16* xq = (_Float16*)d_ws;
    _Float16* wq = (_Float16*)((char*)d_ws + MK * sizeof(_Float16));

    xquant_kernel<<<8192, 256, 0, stream>>>(x, las, laq, ab, xq);
    wquant_kernel<<<8192, 256, 0, stream>>>(w, lws, wq);
    gemm_kernel<<<1024, 512, 0, stream>>>(xq, wq, bias, out);
}

// Round 3
// 331.298 us; speedup vs baseline: 1.2212x; 1.0099x over previous
//
#include <hip/hip_runtime.h>
#include <hip/hip_bf16.h>

// NoisyActLin: y = fakequant(x) @ fakequant(W).T + bias
// x: [4,2048,2048] f32 -> M=8192, K=2048 ; W: [8192,2048] f32 -> N=8192
// out: [8192, 8192] f32
//
// GEMM: 256x256 tile, BK=64, 8 waves, 4 phases/K-tile with one-phase-ahead
// register fragment prefetch (counted lgkm via compiler), T2 st_16x32 swizzle,
// counted vmcnt(8) at P1/P3 ends, setprio around MFMA clusters.

using f16x8 = __attribute__((ext_vector_type(8))) _Float16;
using f32x4 = __attribute__((ext_vector_type(4))) float;

#define AS1 __attribute__((address_space(1)))
#define AS3 __attribute__((address_space(3)))

static __device__ __forceinline__ void gload_lds16(const void* g, void* l) {
    __builtin_amdgcn_global_load_lds((const AS1 void*)g, (AS3 void*)l, 16, 0, 0);
}

// ---------------- weight fake-quant: one block per row ----------------
__global__ __launch_bounds__(256) void wquant_kernel(
    const float* __restrict__ W, const float* __restrict__ lws,
    _Float16* __restrict__ Wq) {
    constexpr int K = 2048;
    const int row = blockIdx.x;
    const int t = threadIdx.x;
    const float* w = W + (size_t)row * K;

    float4 v0 = ((const float4*)w)[t * 2];
    float4 v1 = ((const float4*)w)[t * 2 + 1];
    float vals[8] = {v0.x, v0.y, v0.z, v0.w, v1.x, v1.y, v1.z, v1.w};

    float mn = vals[0], mx = vals[0];
#pragma unroll
    for (int i = 1; i < 8; ++i) {
        mn = fminf(mn, vals[i]);
        mx = fmaxf(mx, vals[i]);
    }
#pragma unroll
    for (int off = 32; off >= 1; off >>= 1) {
        mn = fminf(mn, __shfl_xor(mn, off));
        mx = fmaxf(mx, __shfl_xor(mx, off));
    }
    __shared__ float smn[4], smx[4];
    if ((t & 63) == 0) { smn[t >> 6] = mn; smx[t >> 6] = mx; }
    __syncthreads();
    mn = fminf(fminf(smn[0], smn[1]), fminf(smn[2], smn[3]));
    mx = fmaxf(fmaxf(smx[0], smx[1]), fmaxf(smx[2], smx[3]));

    const float l = lws[row];
    const float ws = exp2f(l);     // power of two -> exact
    const float rs = exp2f(-l);    // exact reciprocal
    const float qwmin = rintf(mn * rs * 2.0f) * 0.5f * ws;
    const float qwmax = rintf(mx * rs * 2.0f) * 0.5f * ws;

    f16x8 out;
#pragma unroll
    for (int i = 0; i < 8; ++i) {
        float c = fminf(fmaxf(vals[i], qwmin), qwmax);
        float qw = rintf((c - qwmin) * rs);
        out[i] = (_Float16)(qw * ws + qwmin);
    }
    *(f16x8*)&Wq[(size_t)row * K + (size_t)t * 8] = out;
}

// ---------------- activation fake-quant: elementwise ----------------
__global__ __launch_bounds__(256) void xquant_kernel(
    const float* __restrict__ X,
    const float* __restrict__ las, const float* __restrict__ laq,
    const float* __restrict__ ab, _Float16* __restrict__ Xq) {
    const float ls = las[0], lq = laq[0];
    const float s = exp2f(ls);
    const float rs = exp2f(-ls);
    const float q = exp2f(lq);
    const float zp = rintf(ab[0] * rs * 2.0f) * 0.5f * s;
    const float lo = zp;
    const float hi = (zp + q) - s;

    const size_t base = ((size_t)blockIdx.x * 256 + threadIdx.x) * 8;
    float4 v0 = *(const float4*)&X[base];
    float4 v1 = *(const float4*)&X[base + 4];
    float vals[8] = {v0.x, v0.y, v0.z, v0.w, v1.x, v1.y, v1.z, v1.w};

    f16x8 out;
#pragma unroll
    for (int i = 0; i < 8; ++i) {
        float c = fminf(fmaxf(vals[i], lo), hi);
        float qx = rintf((c - zp) * rs);
        out[i] = (_Float16)(qx * s + zp);
    }
    *(f16x8*)&Xq[base] = out;
}

// ---------------- GEMM: C[M][N] = A[M][K] * B[N][K]^T + bias ----------------
// LDS: per matrix 4 ring slots [parity][ks] of 256x32 f16 = 16 KB (128 KiB tot).
// st_16x32 swizzle via pre-swizzled global source + swizzled ds_read address.
// Per K-tile t (parity p = t&1), 4 phases; each phase:
//   {issue next-phase ds_reads} {STAGE one slot} {MFMA this phase's frags}
//   [vmcnt(8) at P1/P3 end] {s_barrier}
// Stage schedule: P1->(t+1).A1, P2->(t+2).B0, P3->(t+2).A0, P4->(t+2).B1.
// Ledger (verified):
//   landing: vmcnt(8)@P1-end => landed through (t-1).P1 target (t.A1)  [P2 reads]
//            vmcnt(8)@P3-end => landed through (t-1).P3 target ((t+1).A0) [P4 reads]
//   WAR: every slot's last ds_read completes (compiler lgkm before consuming
//        MFMA) >=1 barrier before the STAGE that overwrites it.
__global__ __launch_bounds__(512, 2) void gemm_kernel(
    const _Float16* __restrict__ A, const _Float16* __restrict__ B,
    const float* __restrict__ bias, float* __restrict__ C) {
    constexpr int N = 8192, K = 2048;
    constexpr int KT = K / 64;          // 32 K-tiles
    constexpr int NBN = N / 256;        // 32

    __shared__ char smem[131072];       // 128 KiB
    char* As = smem;                    // 4 x 16384
    char* Bs = smem + 65536;            // 4 x 16384

    // XCD-aware swizzle (nwg = 1024, %8 == 0 -> bijective)
    const int bid = blockIdx.x;
    const int cpx = gridDim.x >> 3;
    const int swzb = (bid & 7) * cpx + (bid >> 3);
    const int bm = swzb / NBN;
    const int bn = swzb % NBN;

    const int t = threadIdx.x;
    const int lane = t & 63;
    const int wid = t >> 6;
    const int wr = wid >> 2;            // 0..1 (M)
    const int wc = wid & 3;             // 0..3 (N)
    const int l15 = lane & 15;
    const int lq = lane >> 4;

    // staging: chunk covers LDS bytes d..d+15 (linear dest); source element is
    // the swizzled position (st_16x32: byte bit5 ^= bit9).
    const int d0 = t * 16, d1 = (t + 512) * 16;
    const int eoff0 = (d0 >> 6) * K + (((d0 & 63) ^ (((d0 >> 9) & 1) << 5)) >> 1);
    const int eoff1 = (d1 >> 6) * K + (((d1 & 63) ^ (((d1 >> 9) & 1) << 5)) >> 1);
    const _Float16* Agb = A + (size_t)bm * 256 * K;
    const _Float16* Bgb = B + (size_t)bn * 256 * K;

    // read-side swizzled column offset (byte bit9 == row bit3 == l15 bit3)
    const int colpart = (lq * 16) ^ ((l15 & 8) << 2);

    f32x4 acc[8][4] = {};
    f16x8 afA[4], afB[4], bf0[4], bf1[4];

#define STAGE(gb, lm, ktSlot, ktSrc, ks) do {                                  \
        const _Float16* _g = (gb) + ((size_t)(ktSrc) * 64 + (ks) * 32);        \
        char* _l = (lm) + ((((ktSlot) & 1) * 2 + (ks)) * 16384);               \
        gload_lds16(_g + eoff0, _l + d0);                                      \
        gload_lds16(_g + eoff1, _l + d1);                                      \
    } while (0)

#define LDA(dst, par, ks, mh) do {                                             \
        const char* _s = As + ((par) * 2 + (ks)) * 16384;                      \
        _Pragma("unroll")                                                      \
        for (int _m = 0; _m < 4; ++_m)                                         \
            dst[_m] = *(const f16x8*)(_s +                                     \
                (wr * 128 + (mh) * 64 + _m * 16 + l15) * 64 + colpart);        \
    } while (0)

#define LDB(dst, par, ks) do {                                                 \
        const char* _s = Bs + ((par) * 2 + (ks)) * 16384;                      \
        _Pragma("unroll")                                                      \
        for (int _n = 0; _n < 4; ++_n)                                         \
            dst[_n] = *(const f16x8*)(_s +                                     \
                (wc * 64 + _n * 16 + l15) * 64 + colpart);                     \
    } while (0)

#define MFMA16(accRow, afv, bfv) do {                                          \
        _Pragma("unroll")                                                      \
        for (int _m = 0; _m < 4; ++_m)                                         \
            _Pragma("unroll")                                                  \
            for (int _n = 0; _n < 4; ++_n)                                     \
                acc[(accRow) + _m][_n] = __builtin_amdgcn_mfma_f32_16x16x32_f16(\
                    afv[_m], bfv[_n], acc[(accRow) + _m][_n], 0, 0, 0);        \
    } while (0)

    // ---- prologue: stage t0 all + t1.{B0,A0,B1}; wait t0 landed; read P1 ----
    STAGE(Bgb, Bs, 0, 0, 0);
    STAGE(Agb, As, 0, 0, 0);
    STAGE(Bgb, Bs, 0, 0, 1);
    STAGE(Agb, As, 0, 0, 1);
    STAGE(Bgb, Bs, 1, 1, 0);
    STAGE(Agb, As, 1, 1, 0);
    STAGE(Bgb, Bs, 1, 1, 1);
    asm volatile("s_waitcnt vmcnt(6)" ::: "memory");
    __builtin_amdgcn_s_barrier();
    LDA(afA, 0, 0, 0);
    LDB(bf0, 0, 0);

    for (int kt = 0; kt < KT; ++kt) {
        const int par = kt & 1;
        const int npar = par ^ 1;
        const int nx = (kt + 1 < KT) ? kt + 1 : KT - 1;
        const int s2 = (kt + 2 < KT) ? kt + 2 : KT - 1;

        // ===== P1: MFMA(ks0,mh0)=afA*bf0 ; prefetch afB<-A(ks0,mh1) ; stage (kt+1).A1
        LDA(afB, par, 0, 1);
        STAGE(Agb, As, kt + 1, nx, 1);
        __builtin_amdgcn_s_setprio(1);
        MFMA16(0, afA, bf0);
        __builtin_amdgcn_s_setprio(0);
        asm volatile("s_waitcnt vmcnt(8)" ::: "memory");
        __builtin_amdgcn_s_barrier();

        // ===== P2: MFMA(ks0,mh1)=afB*bf0 ; prefetch afA<-A(ks1,mh0), bf1<-B(ks1) ; stage (kt+2).B0
        LDA(afA, par, 1, 0);
        LDB(bf1, par, 1);
        STAGE(Bgb, Bs, kt + 2, s2, 0);
        __builtin_amdgcn_s_setprio(1);
        MFMA16(4, afB, bf0);
        __builtin_amdgcn_s_setprio(0);
        __builtin_amdgcn_s_barrier();

        // ===== P3: MFMA(ks1,mh0)=afA*bf1 ; prefetch afB<-A(ks1,mh1) ; stage (kt+2).A0
        LDA(afB, par, 1, 1);
        STAGE(Agb, As, kt + 2, s2, 0);
        __builtin_amdgcn_s_setprio(1);
        MFMA16(0, afA, bf1);
        __builtin_amdgcn_s_setprio(0);
        asm volatile("s_waitcnt vmcnt(8)" ::: "memory");
        __builtin_amdgcn_s_barrier();

        // ===== P4: MFMA(ks1,mh1)=afB*bf1 ; prefetch next afA<-A(t+1,ks0,mh0), bf0<-B(t+1,ks0) ; stage (kt+2).B1
        LDA(afA, npar, 0, 0);
        LDB(bf0, npar, 0);
        STAGE(Bgb, Bs, kt + 2, s2, 1);
        __builtin_amdgcn_s_setprio(1);
        MFMA16(4, afB, bf1);
        __builtin_amdgcn_s_setprio(0);
        __builtin_amdgcn_s_barrier();
    }
#undef STAGE
#undef LDA
#undef LDB
#undef MFMA16

    // ---- epilogue: C/D mapping col=lane&15, row=(lane>>4)*4+reg ----
#pragma unroll
    for (int m = 0; m < 8; ++m) {
        const int row = bm * 256 + wr * 128 + m * 16 + lq * 4;
#pragma unroll
        for (int n = 0; n < 4; ++n) {
            const int col = bn * 256 + wc * 64 + n * 16 + l15;
            const float bv = bias[col];
#pragma unroll
            for (int r = 0; r < 4; ++r) {
                C[(size_t)(row + r) * N + col] = acc[m][n][r] + bv;
            }
        }
    }
}

extern "C" void kernel_launch(void* const* d_in, const int* in_sizes, int n_in,
                              void* d_out, int out_size, void* d_ws, size_t ws_size,
                              hipStream_t stream) {
    const float* x    = (const float*)d_in[0];   // [4,2048,2048]
    const float* w    = (const float*)d_in[1];   // [8192,2048]
    const float* bias = (const float*)d_in[2];   // [8192]
    const float* las  = (const float*)d_in[3];   // log_act_s [1]
    const float* laq  = (const float*)d_in[4];   // log_act_q [1]
    const float* ab   = (const float*)d_in[5];   // act_b [1]
    const float* lws  = (const float*)d_in[6];   // log_wght_s [8192]
    float* out = (float*)d_out;

    constexpr size_t MK = (size_t)8192 * 2048;
    _Float16* xq = (_Float16*)d_ws;
    _Float16* wq = (_Float16*)((char*)d_ws + MK * sizeof(_Float16));

    xquant_kernel<<<8192, 256, 0, stream>>>(x, las, laq, ab, xq);
    wquant_kernel<<<8192, 256, 0, stream>>>(w, lws, wq);
    gemm_kernel<<<1024, 512, 0, stream>>>(xq, wq, bias, out);
}

// Round 4
// 300.841 us; speedup vs baseline: 1.3448x; 1.1012x over previous
//
#include <hip/hip_runtime.h>
#include <hip/hip_bf16.h>

// NoisyActLin: y = fakequant(x) @ fakequant(W).T + bias
// x: [4,2048,2048] f32 -> M=8192, K=2048 ; W: [8192,2048] f32 -> N=8192
// out: [8192, 8192] f32
//
// GEMM: m201-replica. 256x256 tile, BK=64, 8 waves (2Mx4N), per-wave 128x64.
// LDS 128 KiB: per matrix [dbuf 2][half 2][128 rows][64 k] f16 (16 KB slots).
// 8 phases per 2 K-tiles; quadrant MFMA (16 per phase); frag reads {12,4,8,0};
// st_16x32 swizzle; 1 half-tile stage per phase; vmcnt(4) at P4/P8.

using f16x8 = __attribute__((ext_vector_type(8))) _Float16;
using f32x4 = __attribute__((ext_vector_type(4))) float;

#define AS1 __attribute__((address_space(1)))
#define AS3 __attribute__((address_space(3)))

static __device__ __forceinline__ void gload_lds16(const void* g, void* l) {
    __builtin_amdgcn_global_load_lds((const AS1 void*)g, (AS3 void*)l, 16, 0, 0);
}

// ---------------- weight fake-quant: one block per row ----------------
__global__ __launch_bounds__(256) void wquant_kernel(
    const float* __restrict__ W, const float* __restrict__ lws,
    _Float16* __restrict__ Wq) {
    constexpr int K = 2048;
    const int row = blockIdx.x;
    const int t = threadIdx.x;
    const float* w = W + (size_t)row * K;

    float4 v0 = ((const float4*)w)[t * 2];
    float4 v1 = ((const float4*)w)[t * 2 + 1];
    float vals[8] = {v0.x, v0.y, v0.z, v0.w, v1.x, v1.y, v1.z, v1.w};

    float mn = vals[0], mx = vals[0];
#pragma unroll
    for (int i = 1; i < 8; ++i) {
        mn = fminf(mn, vals[i]);
        mx = fmaxf(mx, vals[i]);
    }
#pragma unroll
    for (int off = 32; off >= 1; off >>= 1) {
        mn = fminf(mn, __shfl_xor(mn, off));
        mx = fmaxf(mx, __shfl_xor(mx, off));
    }
    __shared__ float smn[4], smx[4];
    if ((t & 63) == 0) { smn[t >> 6] = mn; smx[t >> 6] = mx; }
    __syncthreads();
    mn = fminf(fminf(smn[0], smn[1]), fminf(smn[2], smn[3]));
    mx = fmaxf(fmaxf(smx[0], smx[1]), fmaxf(smx[2], smx[3]));

    const float l = lws[row];
    const float ws = exp2f(l);     // power of two -> exact
    const float rs = exp2f(-l);    // exact reciprocal
    const float qwmin = rintf(mn * rs * 2.0f) * 0.5f * ws;
    const float qwmax = rintf(mx * rs * 2.0f) * 0.5f * ws;

    f16x8 out;
#pragma unroll
    for (int i = 0; i < 8; ++i) {
        float c = fminf(fmaxf(vals[i], qwmin), qwmax);
        float qw = rintf((c - qwmin) * rs);
        out[i] = (_Float16)(qw * ws + qwmin);
    }
    *(f16x8*)&Wq[(size_t)row * K + (size_t)t * 8] = out;
}

// ---------------- activation fake-quant: elementwise ----------------
__global__ __launch_bounds__(256) void xquant_kernel(
    const float* __restrict__ X,
    const float* __restrict__ las, const float* __restrict__ laq,
    const float* __restrict__ ab, _Float16* __restrict__ Xq) {
    const float ls = las[0], lq = laq[0];
    const float s = exp2f(ls);
    const float rs = exp2f(-ls);
    const float q = exp2f(lq);
    const float zp = rintf(ab[0] * rs * 2.0f) * 0.5f * s;
    const float lo = zp;
    const float hi = (zp + q) - s;

    const size_t base = ((size_t)blockIdx.x * 256 + threadIdx.x) * 8;
    float4 v0 = *(const float4*)&X[base];
    float4 v1 = *(const float4*)&X[base + 4];
    float vals[8] = {v0.x, v0.y, v0.z, v0.w, v1.x, v1.y, v1.z, v1.w};

    f16x8 out;
#pragma unroll
    for (int i = 0; i < 8; ++i) {
        float c = fminf(fmaxf(vals[i], lo), hi);
        float qx = rintf((c - zp) * rs);
        out[i] = (_Float16)(qx * s + zp);
    }
    *(f16x8*)&Xq[base] = out;
}

// ---------------- GEMM: C[M][N] = A[M][K] * B[N][K]^T + bias ----------------
// Ledger (stage order per iteration i, tiles a=2i[db0], b=2i+1[db1],
// aN=a+2, bN=b+2):
//   P1: b.A0   (db1.A.h0 free since prev P7)
//   P2: b.A1   (db1.A.h1 free since prev P7)
//   P3: aN.B0  (db0.B.h0 free after P2: tile a B read P1,P2)
//   P4: aN.A0  (db0.A.h0 free after P3: tile a A read P1,P3)
//   P5: aN.A1  (after P3)
//   P6: aN.B1  (after P2)
//   P7: bN.B0  (db1.B free after P6: tile b B read P5,P6)
//   P8: bN.B1
// Landing: vmcnt(4)@P4 leaves {aN.A0,aN.B0} -> b.A0/A1 (P1/P2) landed
//   before P5 (tile b first read). vmcnt(4)@P8 leaves {bN.B1,bN.B0} ->
//   aN.B1 (P6) and everything older landed before next-P1.
__global__ __launch_bounds__(512, 2) void gemm_kernel(
    const _Float16* __restrict__ A, const _Float16* __restrict__ B,
    const float* __restrict__ bias, float* __restrict__ C) {
    constexpr int N = 8192, K = 2048;
    constexpr int KT = K / 64;          // 32 K-tiles, 16 iterations
    constexpr int NBN = N / 256;        // 32

    __shared__ char smem[131072];       // A: 0..64K, B: 64K..128K

    // XCD-aware swizzle (nwg = 1024, %8 == 0 -> bijective)
    const int bid = blockIdx.x;
    const int cpx = gridDim.x >> 3;
    const int swzb = (bid & 7) * cpx + (bid >> 3);
    const int bm = swzb / NBN;
    const int bn = swzb % NBN;

    const int t = threadIdx.x;
    const int lane = t & 63;
    const int wid = t >> 6;
    const int wr = wid >> 2;            // 0..1 (M half)
    const int wc = wid & 3;             // 0..3 (N quarter)
    const int l15 = lane & 15;
    const int lq = lane >> 4;

    // staging: half-tile = [128 rows][64 k] f16 = 16384 B, linear LDS dest,
    // pre-swizzled global source (st_16x32: byte bit5 ^= bit9; bit9 = row bit2)
    const int d0 = t * 16, d1 = d0 + 8192;
    const int r0 = d0 >> 7, c0 = (((d0 & 127) ^ (((d0 >> 9) & 1) << 5)) >> 1);
    const int r1 = d1 >> 7, c1 = (((d1 & 127) ^ (((d1 >> 9) & 1) << 5)) >> 1);
    const _Float16* Agb = A + (size_t)bm * 256 * K;
    const _Float16* Bgb = B + (size_t)bn * 256 * K;

    // read-side swizzled k-col byte offset (row bit2 == l15 bit2)
    const int cp = (lq * 16) ^ ((l15 & 4) << 3);

    f32x4 acc[8][4] = {};
    f16x8 fA0[4][2], fA1[4][2], fB0[2][2], fB1[2][2];

#define STAGE(GB, RO, DBS, H, KS) do {                                         \
        const _Float16* _g = (GB) + (size_t)((H) * 128) * K + (size_t)(KS) * 64;\
        char* _l = smem + (RO) + ((DBS) * 2 + (H)) * 16384;                    \
        gload_lds16(_g + (size_t)r0 * K + c0, _l + d0);                        \
        gload_lds16(_g + (size_t)r1 * K + c1, _l + d1);                        \
    } while (0)

#define LDAF(dst, DBv, MLO) do {                                               \
        const char* _s = smem + ((DBv) * 2 + wr) * 16384 + l15 * 128 + cp;     \
        _Pragma("unroll")                                                      \
        for (int _m = 0; _m < 4; ++_m) {                                       \
            dst[_m][0] = *(const f16x8*)(_s + ((MLO) + _m) * 2048);            \
            dst[_m][1] = *(const f16x8*)(_s + ((MLO) + _m) * 2048 + 64);       \
        }                                                                      \
    } while (0)

#define LDBF(dst, DBv, NLO) do {                                               \
        const char* _s = smem + 65536 + ((DBv) * 2 + (wc >> 1)) * 16384 +      \
                         (wc & 1) * 8192 + l15 * 128 + cp;                     \
        _Pragma("unroll")                                                      \
        for (int _n = 0; _n < 2; ++_n) {                                       \
            dst[_n][0] = *(const f16x8*)(_s + ((NLO) + _n) * 2048);            \
            dst[_n][1] = *(const f16x8*)(_s + ((NLO) + _n) * 2048 + 64);       \
        }                                                                      \
    } while (0)

#define QMFMA(MLO, NLO, AF, BF) do {                                           \
        _Pragma("unroll")                                                      \
        for (int _m = 0; _m < 4; ++_m)                                         \
            _Pragma("unroll")                                                  \
            for (int _n = 0; _n < 2; ++_n) {                                   \
                f32x4 _c = acc[(MLO) + _m][(NLO) + _n];                        \
                _c = __builtin_amdgcn_mfma_f32_16x16x32_f16(                   \
                    AF[_m][0], BF[_n][0], _c, 0, 0, 0);                        \
                _c = __builtin_amdgcn_mfma_f32_16x16x32_f16(                   \
                    AF[_m][1], BF[_n][1], _c, 0, 0, 0);                        \
                acc[(MLO) + _m][(NLO) + _n] = _c;                              \
            }                                                                  \
    } while (0)

// one K-tile = 4 phases. Quadrant order: (m0,n0)r12, (m0,n1)r4, (m1,n1)r8, (m1,n0)r0.
#define HALFITER(DBv, S1, S2, S3, S4, VMW) do {                                \
        /* P1: 12 ds_reads */                                                  \
        LDAF(fA0, DBv, 0); LDBF(fB0, DBv, 0);                                  \
        S1;                                                                    \
        asm volatile("s_waitcnt lgkmcnt(8)" ::: "memory");                     \
        __builtin_amdgcn_s_barrier();                                          \
        asm volatile("s_waitcnt lgkmcnt(0)" ::: "memory");                     \
        __builtin_amdgcn_s_setprio(1);                                         \
        QMFMA(0, 0, fA0, fB0);                                                 \
        __builtin_amdgcn_s_setprio(0);                                         \
        __builtin_amdgcn_s_barrier();                                          \
        /* P2: 4 ds_reads */                                                   \
        LDBF(fB1, DBv, 2);                                                     \
        S2;                                                                    \
        __builtin_amdgcn_s_barrier();                                          \
        asm volatile("s_waitcnt lgkmcnt(0)" ::: "memory");                     \
        __builtin_amdgcn_s_setprio(1);                                         \
        QMFMA(0, 2, fA0, fB1);                                                 \
        __builtin_amdgcn_s_setprio(0);                                         \
        __builtin_amdgcn_s_barrier();                                          \
        /* P3: 8 ds_reads */                                                   \
        LDAF(fA1, DBv, 4);                                                     \
        S3;                                                                    \
        __builtin_amdgcn_s_barrier();                                          \
        asm volatile("s_waitcnt lgkmcnt(0)" ::: "memory");                     \
        __builtin_amdgcn_s_setprio(1);                                         \
        QMFMA(4, 2, fA1, fB1);                                                 \
        __builtin_amdgcn_s_setprio(0);                                         \
        __builtin_amdgcn_s_barrier();                                          \
        /* P4: 0 ds_reads */                                                   \
        S4;                                                                    \
        __builtin_amdgcn_s_barrier();                                          \
        __builtin_amdgcn_s_setprio(1);                                         \
        QMFMA(4, 0, fA1, fB0);                                                 \
        __builtin_amdgcn_s_setprio(0);                                         \
        asm volatile("s_waitcnt vmcnt(" #VMW ")" ::: "memory");                \
        __builtin_amdgcn_s_barrier();                                          \
    } while (0)

    // ---- prologue: stage t0 all + t1.B0/B1; wait t0 landed ----
    STAGE(Bgb, 65536, 0, 0, 0);   // t0.B0
    STAGE(Agb, 0,     0, 0, 0);   // t0.A0
    STAGE(Agb, 0,     0, 1, 0);   // t0.A1
    STAGE(Bgb, 65536, 0, 1, 0);   // t0.B1
    STAGE(Bgb, 65536, 1, 0, 1);   // t1.B0
    STAGE(Bgb, 65536, 1, 1, 1);   // t1.B1
    asm volatile("s_waitcnt vmcnt(4)" ::: "memory");
    __builtin_amdgcn_s_barrier();

    for (int it = 0; it < KT / 2; ++it) {
        const int b  = 2 * it + 1;
        const int aN = (2 * it + 2 < KT) ? 2 * it + 2 : KT - 2;
        const int bN = (2 * it + 3 < KT) ? 2 * it + 3 : KT - 1;

        // tile a (db0): stages P1..P4 = b.A0, b.A1, aN.B0, aN.A0
        HALFITER(0,
                 STAGE(Agb, 0,     1, 0, b),
                 STAGE(Agb, 0,     1, 1, b),
                 STAGE(Bgb, 65536, 0, 0, aN),
                 STAGE(Agb, 0,     0, 0, aN), 4);
        // tile b (db1): stages P5..P8 = aN.A1, aN.B1, bN.B0, bN.B1
        HALFITER(1,
                 STAGE(Agb, 0,     0, 1, aN),
                 STAGE(Bgb, 65536, 0, 1, aN),
                 STAGE(Bgb, 65536, 1, 0, bN),
                 STAGE(Bgb, 65536, 1, 1, bN), 4);
    }
#undef HALFITER
#undef QMFMA
#undef LDBF
#undef LDAF
#undef STAGE

    // ---- epilogue: C/D mapping col=lane&15, row=(lane>>4)*4+reg ----
#pragma unroll
    for (int m = 0; m < 8; ++m) {
        const int row = bm * 256 + wr * 128 + m * 16 + lq * 4;
#pragma unroll
        for (int n = 0; n < 4; ++n) {
            const int col = bn * 256 + wc * 64 + n * 16 + l15;
            const float bv = bias[col];
#pragma unroll
            for (int r = 0; r < 4; ++r) {
                C[(size_t)(row + r) * N + col] = acc[m][n][r] + bv;
            }
        }
    }
}

extern "C" void kernel_launch(void* const* d_in, const int* in_sizes, int n_in,
                              void* d_out, int out_size, void* d_ws, size_t ws_size,
                              hipStream_t stream) {
    const float* x    = (const float*)d_in[0];   // [4,2048,2048]
    const float* w    = (const float*)d_in[1];   // [8192,2048]
    const float* bias = (const float*)d_in[2];   // [8192]
    const float* las  = (const float*)d_in[3];   // log_act_s [1]
    const float* laq  = (const float*)d_in[4];   // log_act_q [1]
    const float* ab   = (const float*)d_in[5];   // act_b [1]
    const float* lws  = (const float*)d_in[6];   // log_wght_s [8192]
    float* out = (float*)d_out;

    constexpr size_t MK = (size_t)8192 * 2048;
    _Float16* xq = (_Float16*)d_ws;
    _Float16* wq = (_Float16*)((char*)d_ws + MK * sizeof(_Float16));

    xquant_kernel<<<8192, 256, 0, stream>>>(x, las, laq, ab, xq);
    wquant_kernel<<<8192, 256, 0, stream>>>(w, lws, wq);
    gemm_kernel<<<1024, 512, 0, stream>>>(xq, wq, bias, out);
}

// Round 5
// 290.281 us; speedup vs baseline: 1.3937x; 1.0364x over previous
//
#include <hip/hip_runtime.h>
#include <hip/hip_bf16.h>

// NoisyActLin: y = fakequant(x) @ fakequant(W).T + bias
// x: [4,2048,2048] f32 -> M=8192, K=2048 ; W: [8192,2048] f32 -> N=8192
// out: [8192, 8192] f32
//
// GEMM: m201-replica. 256x256 tile, BK=64, 8 waves (2Mx4N), per-wave 128x64.
// LDS 128 KiB: per matrix [dbuf 2][half 2][128 rows][64 k] f16 (16 KB slots).
// 8 phases per 2 K-tiles; quadrant MFMA (16 per phase); frag reads {12,4,8,0};
// T2 swizzle byte ^= (row&7)<<4 (3-bit — 128B rows need full 8-row spread);
// 1 half-tile stage per phase; counted vmcnt(4) at P4/P8.

using f16x8 = __attribute__((ext_vector_type(8))) _Float16;
using f32x4 = __attribute__((ext_vector_type(4))) float;

#define AS1 __attribute__((address_space(1)))
#define AS3 __attribute__((address_space(3)))

static __device__ __forceinline__ void gload_lds16(const void* g, void* l) {
    __builtin_amdgcn_global_load_lds((const AS1 void*)g, (AS3 void*)l, 16, 0, 0);
}

// ---------------- weight fake-quant: one block per row ----------------
__global__ __launch_bounds__(256) void wquant_kernel(
    const float* __restrict__ W, const float* __restrict__ lws,
    _Float16* __restrict__ Wq) {
    constexpr int K = 2048;
    const int row = blockIdx.x;
    const int t = threadIdx.x;
    const float* w = W + (size_t)row * K;

    float4 v0 = ((const float4*)w)[t * 2];
    float4 v1 = ((const float4*)w)[t * 2 + 1];
    float vals[8] = {v0.x, v0.y, v0.z, v0.w, v1.x, v1.y, v1.z, v1.w};

    float mn = vals[0], mx = vals[0];
#pragma unroll
    for (int i = 1; i < 8; ++i) {
        mn = fminf(mn, vals[i]);
        mx = fmaxf(mx, vals[i]);
    }
#pragma unroll
    for (int off = 32; off >= 1; off >>= 1) {
        mn = fminf(mn, __shfl_xor(mn, off));
        mx = fmaxf(mx, __shfl_xor(mx, off));
    }
    __shared__ float smn[4], smx[4];
    if ((t & 63) == 0) { smn[t >> 6] = mn; smx[t >> 6] = mx; }
    __syncthreads();
    mn = fminf(fminf(smn[0], smn[1]), fminf(smn[2], smn[3]));
    mx = fmaxf(fmaxf(smx[0], smx[1]), fmaxf(smx[2], smx[3]));

    const float l = lws[row];
    const float ws = exp2f(l);     // power of two -> exact
    const float rs = exp2f(-l);    // exact reciprocal
    const float qwmin = rintf(mn * rs * 2.0f) * 0.5f * ws;
    const float qwmax = rintf(mx * rs * 2.0f) * 0.5f * ws;

    f16x8 out;
#pragma unroll
    for (int i = 0; i < 8; ++i) {
        float c = fminf(fmaxf(vals[i], qwmin), qwmax);
        float qw = rintf((c - qwmin) * rs);
        out[i] = (_Float16)(qw * ws + qwmin);
    }
    *(f16x8*)&Wq[(size_t)row * K + (size_t)t * 8] = out;
}

// ---------------- activation fake-quant: elementwise ----------------
__global__ __launch_bounds__(256) void xquant_kernel(
    const float* __restrict__ X,
    const float* __restrict__ las, const float* __restrict__ laq,
    const float* __restrict__ ab, _Float16* __restrict__ Xq) {
    const float ls = las[0], lq = laq[0];
    const float s = exp2f(ls);
    const float rs = exp2f(-ls);
    const float q = exp2f(lq);
    const float zp = rintf(ab[0] * rs * 2.0f) * 0.5f * s;
    const float lo = zp;
    const float hi = (zp + q) - s;

    const size_t base = ((size_t)blockIdx.x * 256 + threadIdx.x) * 8;
    float4 v0 = *(const float4*)&X[base];
    float4 v1 = *(const float4*)&X[base + 4];
    float vals[8] = {v0.x, v0.y, v0.z, v0.w, v1.x, v1.y, v1.z, v1.w};

    f16x8 out;
#pragma unroll
    for (int i = 0; i < 8; ++i) {
        float c = fminf(fmaxf(vals[i], lo), hi);
        float qx = rintf((c - zp) * rs);
        out[i] = (_Float16)(qx * s + zp);
    }
    *(f16x8*)&Xq[base] = out;
}

// ---------------- GEMM: C[M][N] = A[M][K] * B[N][K]^T + bias ----------------
// Ledger (stage order per iteration i, tiles a=2i[db0], b=2i+1[db1],
// aN=a+2, bN=b+2):
//   P1: b.A0   P2: b.A1   P3: aN.B0   P4: aN.A0  | vmcnt(4)
//   P5: aN.A1  P6: aN.B1  P7: bN.B0   P8: bN.B1  | vmcnt(4)
// WAR: every slot's last ds_read completes >=1 barrier before its overwrite.
// Landing: vmcnt(4)@P4 => b.A0/A1 landed before P5; vmcnt(4)@P8 => aN.* landed
// before next-P1.
__global__ __launch_bounds__(512, 2) void gemm_kernel(
    const _Float16* __restrict__ A, const _Float16* __restrict__ B,
    const float* __restrict__ bias, float* __restrict__ C) {
    constexpr int N = 8192, K = 2048;
    constexpr int KT = K / 64;          // 32 K-tiles, 16 iterations
    constexpr int NBN = N / 256;        // 32

    __shared__ char smem[131072];       // A: 0..64K, B: 64K..128K

    // XCD-aware swizzle (nwg = 1024, %8 == 0 -> bijective)
    const int bid = blockIdx.x;
    const int cpx = gridDim.x >> 3;
    const int swzb = (bid & 7) * cpx + (bid >> 3);
    const int bm = swzb / NBN;
    const int bn = swzb % NBN;

    const int t = threadIdx.x;
    const int lane = t & 63;
    const int wid = t >> 6;
    const int wr = wid >> 2;            // 0..1 (M half)
    const int wc = wid & 3;             // 0..3 (N quarter)
    const int l15 = lane & 15;
    const int lq = lane >> 4;

    // staging: half-tile = [128 rows][64 k] f16 = 16384 B, linear LDS dest,
    // pre-swizzled global source. T2 swizzle: byte ^= (row&7)<<4.
    const int d0 = t * 16, d1 = d0 + 8192;
    const int r0 = d0 >> 7, c0 = (((d0 & 127) ^ (((d0 >> 7) & 7) << 4)) >> 1);
    const int r1 = d1 >> 7, c1 = (((d1 & 127) ^ (((d1 >> 7) & 7) << 4)) >> 1);
    const _Float16* Agb = A + (size_t)bm * 256 * K;
    const _Float16* Bgb = B + (size_t)bn * 256 * K;

    // read-side swizzled k-col byte offsets (frag row&7 == l15&7)
    const int cp0 = (lq * 16) ^ ((l15 & 7) << 4);
    const int cp1 = cp0 ^ 64;           // second K-half: XOR, not add (bit6)

    f32x4 acc[8][4] = {};
    f16x8 fA0[4][2], fA1[4][2], fB0[2][2], fB1[2][2];

#define STAGE(GB, RO, DBS, H, KS) do {                                         \
        const _Float16* _g = (GB) + (size_t)((H) * 128) * K + (size_t)(KS) * 64;\
        char* _l = smem + (RO) + ((DBS) * 2 + (H)) * 16384;                    \
        gload_lds16(_g + (size_t)r0 * K + c0, _l + d0);                        \
        gload_lds16(_g + (size_t)r1 * K + c1, _l + d1);                        \
    } while (0)

#define LDAF(dst, DBv, MLO) do {                                               \
        const char* _s = smem + ((DBv) * 2 + wr) * 16384 + l15 * 128;          \
        _Pragma("unroll")                                                      \
        for (int _m = 0; _m < 4; ++_m) {                                       \
            dst[_m][0] = *(const f16x8*)(_s + ((MLO) + _m) * 2048 + cp0);      \
            dst[_m][1] = *(const f16x8*)(_s + ((MLO) + _m) * 2048 + cp1);      \
        }                                                                      \
    } while (0)

#define LDBF(dst, DBv, NLO) do {                                               \
        const char* _s = smem + 65536 + ((DBv) * 2 + (wc >> 1)) * 16384 +      \
                         (wc & 1) * 8192 + l15 * 128;                          \
        _Pragma("unroll")                                                      \
        for (int _n = 0; _n < 2; ++_n) {                                       \
            dst[_n][0] = *(const f16x8*)(_s + ((NLO) + _n) * 2048 + cp0);      \
            dst[_n][1] = *(const f16x8*)(_s + ((NLO) + _n) * 2048 + cp1);      \
        }                                                                      \
    } while (0)

#define QMFMA(MLO, NLO, AF, BF) do {                                           \
        _Pragma("unroll")                                                      \
        for (int _m = 0; _m < 4; ++_m)                                         \
            _Pragma("unroll")                                                  \
            for (int _n = 0; _n < 2; ++_n) {                                   \
                f32x4 _c = acc[(MLO) + _m][(NLO) + _n];                        \
                _c = __builtin_amdgcn_mfma_f32_16x16x32_f16(                   \
                    AF[_m][0], BF[_n][0], _c, 0, 0, 0);                        \
                _c = __builtin_amdgcn_mfma_f32_16x16x32_f16(                   \
                    AF[_m][1], BF[_n][1], _c, 0, 0, 0);                        \
                acc[(MLO) + _m][(NLO) + _n] = _c;                              \
            }                                                                  \
    } while (0)

// one K-tile = 4 phases. Quadrant order: (m0,n0)r12, (m0,n1)r4, (m1,n1)r8, (m1,n0)r0.
#define HALFITER(DBv, S1, S2, S3, S4, VMW) do {                                \
        /* P1: 12 ds_reads */                                                  \
        LDAF(fA0, DBv, 0); LDBF(fB0, DBv, 0);                                  \
        S1;                                                                    \
        asm volatile("s_waitcnt lgkmcnt(8)" ::: "memory");                     \
        __builtin_amdgcn_s_barrier();                                          \
        asm volatile("s_waitcnt lgkmcnt(0)" ::: "memory");                     \
        __builtin_amdgcn_s_setprio(1);                                         \
        QMFMA(0, 0, fA0, fB0);                                                 \
        __builtin_amdgcn_s_setprio(0);                                         \
        __builtin_amdgcn_s_barrier();                                          \
        /* P2: 4 ds_reads */                                                   \
        LDBF(fB1, DBv, 2);                                                     \
        S2;                                                                    \
        __builtin_amdgcn_s_barrier();                                          \
        asm volatile("s_waitcnt lgkmcnt(0)" ::: "memory");                     \
        __builtin_amdgcn_s_setprio(1);                                         \
        QMFMA(0, 2, fA0, fB1);                                                 \
        __builtin_amdgcn_s_setprio(0);                                         \
        __builtin_amdgcn_s_barrier();                                          \
        /* P3: 8 ds_reads */                                                   \
        LDAF(fA1, DBv, 4);                                                     \
        S3;                                                                    \
        __builtin_amdgcn_s_barrier();                                          \
        asm volatile("s_waitcnt lgkmcnt(0)" ::: "memory");                     \
        __builtin_amdgcn_s_setprio(1);                                         \
        QMFMA(4, 2, fA1, fB1);                                                 \
        __builtin_amdgcn_s_setprio(0);                                         \
        __builtin_amdgcn_s_barrier();                                          \
        /* P4: 0 ds_reads */                                                   \
        S4;                                                                    \
        __builtin_amdgcn_s_barrier();                                          \
        __builtin_amdgcn_s_setprio(1);                                         \
        QMFMA(4, 0, fA1, fB0);                                                 \
        __builtin_amdgcn_s_setprio(0);                                         \
        asm volatile("s_waitcnt vmcnt(" #VMW ")" ::: "memory");                \
        __builtin_amdgcn_s_barrier();                                          \
    } while (0)

    // ---- prologue: stage t0 all + t1.B0/B1; wait t0 landed ----
    STAGE(Bgb, 65536, 0, 0, 0);   // t0.B0
    STAGE(Agb, 0,     0, 0, 0);   // t0.A0
    STAGE(Agb, 0,     0, 1, 0);   // t0.A1
    STAGE(Bgb, 65536, 0, 1, 0);   // t0.B1
    STAGE(Bgb, 65536, 1, 0, 1);   // t1.B0
    STAGE(Bgb, 65536, 1, 1, 1);   // t1.B1
    asm volatile("s_waitcnt vmcnt(4)" ::: "memory");
    __builtin_amdgcn_s_barrier();

    for (int it = 0; it < KT / 2; ++it) {
        const int b  = 2 * it + 1;
        const int aN = (2 * it + 2 < KT) ? 2 * it + 2 : KT - 2;
        const int bN = (2 * it + 3 < KT) ? 2 * it + 3 : KT - 1;

        // tile a (db0): stages P1..P4 = b.A0, b.A1, aN.B0, aN.A0
        HALFITER(0,
                 STAGE(Agb, 0,     1, 0, b),
                 STAGE(Agb, 0,     1, 1, b),
                 STAGE(Bgb, 65536, 0, 0, aN),
                 STAGE(Agb, 0,     0, 0, aN), 4);
        // tile b (db1): stages P5..P8 = aN.A1, aN.B1, bN.B0, bN.B1
        HALFITER(1,
                 STAGE(Agb, 0,     0, 1, aN),
                 STAGE(Bgb, 65536, 0, 1, aN),
                 STAGE(Bgb, 65536, 1, 0, bN),
                 STAGE(Bgb, 65536, 1, 1, bN), 4);
    }
#undef HALFITER
#undef QMFMA
#undef LDBF
#undef LDAF
#undef STAGE

    // ---- epilogue: C/D mapping col=lane&15, row=(lane>>4)*4+reg ----
#pragma unroll
    for (int m = 0; m < 8; ++m) {
        const int row = bm * 256 + wr * 128 + m * 16 + lq * 4;
#pragma unroll
        for (int n = 0; n < 4; ++n) {
            const int col = bn * 256 + wc * 64 + n * 16 + l15;
            const float bv = bias[col];
#pragma unroll
            for (int r = 0; r < 4; ++r) {
                C[(size_t)(row + r) * N + col] = acc[m][n][r] + bv;
            }
        }
    }
}

extern "C" void kernel_launch(void* const* d_in, const int* in_sizes, int n_in,
                              void* d_out, int out_size, void* d_ws, size_t ws_size,
                              hipStream_t stream) {
    const float* x    = (const float*)d_in[0];   // [4,2048,2048]
    const float* w    = (const float*)d_in[1];   // [8192,2048]
    const float* bias = (const float*)d_in[2];   // [8192]
    const float* las  = (const float*)d_in[3];   // log_act_s [1]
    const float* laq  = (const float*)d_in[4];   // log_act_q [1]
    const float* ab   = (const float*)d_in[5];   // act_b [1]
    const float* lws  = (const float*)d_in[6];   // log_wght_s [8192]
    float* out = (float*)d_out;

    constexpr size_t MK = (size_t)8192 * 2048;
    _Float16* xq = (_Float16*)d_ws;
    _Float16* wq = (_Float16*)((char*)d_ws + MK * sizeof(_Float16));

    xquant_kernel<<<8192, 256, 0, stream>>>(x, las, laq, ab, xq);
    wquant_kernel<<<8192, 256, 0, stream>>>(w, lws, wq);
    gemm_kernel<<<1024, 512, 0, stream>>>(xq, wq, bias, out);
}